// Round 17
// baseline (163.209 us; speedup 1.0000x reference)
//
#include <hip/hip_runtime.h>

#define NCLS 13
#define DIM  256
// (1/0.07) * log2(e): folds temperature AND exp2-domain conversion into A's scale
#define SCL  20.609929155f

typedef float f32x4 __attribute__((ext_vector_type(4)));
typedef int   v8i   __attribute__((ext_vector_type(8)));

__device__ __forceinline__ float bf2f(unsigned u16){
  union { unsigned u; float f; } v; v.u = u16 << 16; return v.f;
}
__device__ __forceinline__ unsigned f2bf(float f){
  union { float f; unsigned u; } v; v.f = f;
  unsigned r = v.u + 0x7fffu + ((v.u >> 16) & 1u);
  return r >> 16;
}
// pack 4 floats -> 4 fp8 e4m3 bytes
__device__ __forceinline__ unsigned pk4fp8(float f0, float f1, float f2, float f3){
  unsigned u = __builtin_amdgcn_cvt_pk_fp8_f32(f0, f1, 0, false);
  return (unsigned)__builtin_amdgcn_cvt_pk_fp8_f32(f2, f3, u, true);
}
__device__ __forceinline__ v8i mkv8(uint4 q0, uint4 q1){
  v8i r;
  r[0] = (int)q0.x; r[1] = (int)q0.y; r[2] = (int)q0.z; r[3] = (int)q0.w;
  r[4] = (int)q1.x; r[5] = (int)q1.y; r[6] = (int)q1.z; r[7] = (int)q1.w;
  return r;
}
// fp8 e4m3 MFMA, K=128, unit MX scales (e8m0 0x7f = 2^0) -> bit-compatible with
// non-scaled fp8 product, ~2.3x the rate, 1/4 the instruction count.
#define MFMA128(A, B, C) __builtin_amdgcn_mfma_scale_f32_16x16x128_f8f6f4( \
    (A), (B), (C), 0, 0, 0, 0x7f7f7f7f, 0, 0x7f7f7f7f)

// ---------------- prep kernels ----------------

__global__ void k_zero(int* counts, unsigned* packLab, double* accum, int n, int np){
  int i = blockIdx.x*blockDim.x + threadIdx.x;
  if (i < n)  counts[i] = 0;
  if (i < np) packLab[i] = 0u;
  if (i == 0) *accum = 0.0;
}

__global__ void k_hist(const int* __restrict__ idx, const int* __restrict__ lab,
                       int* __restrict__ counts, int n){
  int i = blockIdx.x*blockDim.x + threadIdx.x;
  if (i < n) atomicAdd(&counts[idx[i]*NCLS + lab[i]], 1);
}

// one block, M threads. argmax labels + label-sorted permutation + nibble-packed
// column labels for 64-col groups: packLab[(pos>>6)*16 + (pos&15)], nibble (pos>>4)&3.
__global__ void k_label_perm(const int* __restrict__ counts, int* __restrict__ spLabel,
                             int* __restrict__ newpos, unsigned* __restrict__ packLab){
  int m = threadIdx.x;
  int best = 0; int bc = counts[m*NCLS];
  #pragma unroll
  for (int c = 1; c < NCLS; ++c){ int v = counts[m*NCLS+c]; if (v > bc){ bc = v; best = c; } }
  spLabel[m] = best;

  __shared__ int waveCnt[16][NCLS];
  __shared__ int waveOff[16][NCLS];
  __shared__ int classTot[NCLS];
  __shared__ int classBase[NCLS];
  int lane = m & 63, wid = m >> 6;
  int nw = blockDim.x >> 6;
  int rankInWave = 0;
  unsigned long long below = (1ull << lane) - 1ull;
  for (int c = 0; c < NCLS; ++c){
    unsigned long long bal = __ballot(best == c);
    if (best == c) rankInWave = __popcll(bal & below);
    if (lane == 0) waveCnt[wid][c] = __popcll(bal);
  }
  __syncthreads();
  if (m < NCLS){
    int c = m, s = 0;
    for (int w = 0; w < nw; ++w){ waveOff[w][c] = s; s += waveCnt[w][c]; }
    classTot[c] = s;
  }
  __syncthreads();
  if (m == 0){ int s = 0; for (int c = 0; c < NCLS; ++c){ classBase[c] = s; s += classTot[c]; } }
  __syncthreads();
  int pos = classBase[best] + waveOff[wid][best] + rankInWave;
  newpos[m] = pos;
  atomicOr(&packLab[(pos >> 6)*16 + (pos & 15)], (unsigned)best << (((pos >> 4) & 3)*4));
}

// one wave per superpoint row: normalize; write spnO (bf16, linear, for pos logits)
// and spnP8 (fp8 e4m3, label-permuted row, PLAIN row-major [pos][k]).
__global__ void k_norm_sp(const float* __restrict__ sp, const int* __restrict__ newpos,
                          unsigned short* __restrict__ spnO, unsigned char* __restrict__ spnP8){
  int m = blockIdx.x, lane = threadIdx.x;
  const float4 v = *(const float4*)(sp + (size_t)m*DIM + lane*4);
  float ss = v.x*v.x + v.y*v.y + v.z*v.z + v.w*v.w;
  #pragma unroll
  for (int o = 1; o < 64; o <<= 1) ss += __shfl_xor(ss, o);
  float rn = 1.0f / sqrtf(ss + 1e-12f);
  uint2 w;
  w.x = f2bf(v.x*rn) | (f2bf(v.y*rn) << 16);
  w.y = f2bf(v.z*rn) | (f2bf(v.w*rn) << 16);
  *(uint2*)(spnO + (size_t)m*DIM + lane*4) = w;
  unsigned pk = pk4fp8(v.x*rn, v.y*rn, v.z*rn, v.w*rn);
  int p = newpos[m];
  ((unsigned*)spnP8)[p*64 + lane] = pk;     // plain: k = 4*lane..+3
}

// ---------------- main fused GEMM (MX-fp8 K=128, B streamed global->reg) ----------------
// 512 threads = 8 waves; wave owns 32 rows x all 1024 cols. BM=256, grid 512,
// 2 blocks/CU = 4 waves/SIMD (R15/R16 skeleton). B now streams STRAIGHT from
// L2 into a depth-2 ping-pong register set (4 x global_load_dwordx4 per chunk,
// issued one chunk ahead; compiler's auto-waitcnt = counted vmcnt(4)).
// Deletes the whole B-LDS round-trip: gload_lds, ds_reads, lgkm drains,
// swizzle math, bank conflicts. A: fp8 in regs via wave-private LDS staging.

__attribute__((amdgpu_waves_per_eu(1, 4)))
__launch_bounds__(512)
__global__ void k_main(const float* __restrict__ rp, const int* __restrict__ rawIdx,
                       const unsigned short* __restrict__ spnO, const unsigned char* __restrict__ spnP8,
                       const unsigned* __restrict__ packLab, const int* __restrict__ spLabel,
                       double* __restrict__ accum, int M){
  __shared__ __align__(16) char Ast[65536];   // 8 KB per wave: A staging slots
  __shared__ float    posLt[256];
  __shared__ int      posLb[256];
  __shared__ unsigned cpLds[256];
  __shared__ float    lossW[8];

  const int tid  = threadIdx.x;
  const int lane = tid & 63, wid = tid >> 6;
  const int l15  = lane & 15, l4 = lane >> 4;
  const int rowBlock = blockIdx.x * 256;
  char* wb = Ast + wid*8192;                  // this wave's 32 slots x 256 B

  if (tid < 256) cpLds[tid] = packLab[tid];
  if (lane < 32){
    int r = wid*32 + lane;
    posLb[r] = spLabel[rawIdx[rowBlock + r]];
  }

  // ---- prologue: normalize 32 rows/wave -> fp8 into wave-private LDS slots ----
  v8i a[2][2];   // [row-tile p][K-half h]
  #pragma unroll
  for (int p = 0; p < 2; ++p){
    for (int it = 0; it < 4; ++it){
      const int rl = p*16 + it*4 + l4;             // wave-local row (= slot)
      const int t  = l15;
      const float* rpp = rp + (size_t)(rowBlock + wid*32 + rl)*DIM + t*16;
      const float4 v0 = *(const float4*)(rpp);
      const float4 v1 = *(const float4*)(rpp + 4);
      const float4 v2 = *(const float4*)(rpp + 8);
      const float4 v3 = *(const float4*)(rpp + 12);
      float ss = v0.x*v0.x + v0.y*v0.y + v0.z*v0.z + v0.w*v0.w
               + v1.x*v1.x + v1.y*v1.y + v1.z*v1.z + v1.w*v1.w
               + v2.x*v2.x + v2.y*v2.y + v2.z*v2.z + v2.w*v2.w
               + v3.x*v3.x + v3.y*v3.y + v3.z*v3.z + v3.w*v3.w;
      const int sidx = rawIdx[rowBlock + wid*32 + rl];
      const uint4 s0 = *(const uint4*)(spnO + (size_t)sidx*DIM + t*16);
      const uint4 s1 = *(const uint4*)(spnO + (size_t)sidx*DIM + t*16 + 8);
      float dr =
        v0.x*bf2f(s0.x & 0xffff) + v0.y*bf2f(s0.x >> 16) +
        v0.z*bf2f(s0.y & 0xffff) + v0.w*bf2f(s0.y >> 16) +
        v1.x*bf2f(s0.z & 0xffff) + v1.y*bf2f(s0.z >> 16) +
        v1.z*bf2f(s0.w & 0xffff) + v1.w*bf2f(s0.w >> 16) +
        v2.x*bf2f(s1.x & 0xffff) + v2.y*bf2f(s1.x >> 16) +
        v2.z*bf2f(s1.y & 0xffff) + v2.w*bf2f(s1.y >> 16) +
        v3.x*bf2f(s1.z & 0xffff) + v3.y*bf2f(s1.z >> 16) +
        v3.z*bf2f(s1.w & 0xffff) + v3.w*bf2f(s1.w >> 16);
      ss += __shfl_xor(ss, 1); dr += __shfl_xor(dr, 1);
      ss += __shfl_xor(ss, 2); dr += __shfl_xor(dr, 2);
      ss += __shfl_xor(ss, 4); dr += __shfl_xor(dr, 4);
      ss += __shfl_xor(ss, 8); dr += __shfl_xor(dr, 8);
      const float rn = SCL / sqrtf(ss + 1e-12f);
      const int slot = rl;
      const int swz  = (slot & 7) << 4;
      uint4 h;
      h.x = pk4fp8(v0.x*rn, v0.y*rn, v0.z*rn, v0.w*rn);
      h.y = pk4fp8(v1.x*rn, v1.y*rn, v1.z*rn, v1.w*rn);
      h.z = pk4fp8(v2.x*rn, v2.y*rn, v2.z*rn, v2.w*rn);
      h.w = pk4fp8(v3.x*rn, v3.y*rn, v3.z*rn, v3.w*rn);
      *(uint4*)(wb + slot*256 + ((t*16) ^ swz)) = h;   // plain k [t*16,+16) -> swz image
      if (l15 == 0) posLt[wid*32 + rl] = rn * dr;
    }
    // frag reads: slots written by THIS wave (same-wave LDS ordering)
    #pragma unroll
    for (int h = 0; h < 2; ++h){
      const int s   = p*16 + l15;
      const int swz = (l15 & 7) << 4;
      const int off = (h*128 + l4*32) ^ swz;
      uint4 q0 = *(const uint4*)(wb + s*256 + off);
      uint4 q1 = *(const uint4*)(wb + s*256 + (off ^ 16));
      a[p][h] = mkv8(q0, q1);
    }
  }

  // row labels as plain registers (ri = rt*4+e -> wave-local row rt*16 + l4*4 + e)
  unsigned lrv[8];
  #pragma unroll
  for (int rt = 0; rt < 2; ++rt)
    #pragma unroll
    for (int e = 0; e < 4; ++e)
      lrv[rt*4 + e] = (unsigned)posLb[wid*32 + rt*16 + l4*4 + e];

  float sumT[8], sumO[8];
  #pragma unroll
  for (int i = 0; i < 8; ++i){ sumT[i] = 0.f; sumO[i] = 0.f; }

  __syncthreads();   // cpLds visible to all waves (the ONLY mid-kernel barrier)

  // ---- K loop: B streamed global->reg, depth-2 ping-pong, NO barriers ----
  const char* bbase = (const char*)spnP8 + l15*256 + l4*32;

  uint4 xA0, xA1, xA2, xA3, xB0, xB1, xB2, xB3;
  { const char* p0 = bbase;
    xA0 = *(const uint4*)(p0);       xA1 = *(const uint4*)(p0 + 16);
    xA2 = *(const uint4*)(p0 + 128); xA3 = *(const uint4*)(p0 + 144); }

#define EPILOG(CIDX, ACC0, ACC1)                                             \
  do {                                                                       \
    const unsigned colLab = (cpLds[((CIDX) >> 2)*16 + l15] >> (((CIDX) & 3)*4)) & 15u; \
    _Pragma("unroll")                                                        \
    for (int e = 0; e < 4; ++e){                                             \
      const float ev0 = __builtin_amdgcn_exp2f((ACC0)[e]);                   \
      const float ev1 = __builtin_amdgcn_exp2f((ACC1)[e]);                   \
      sumT[e]   += ev0;                                                      \
      sumT[4+e] += ev1;                                                      \
      sumO[e]   += (lrv[e]   == colLab) ? ev0 : 0.f;                         \
      sumO[4+e] += (lrv[4+e] == colLab) ? ev1 : 0.f;                         \
    }                                                                        \
  } while (0)

  for (int c = 0; c < 64; c += 2){
    // issue loads for chunk c+1 (always valid: c <= 62)
    { const char* p1 = bbase + (size_t)(c + 1)*4096;
      xB0 = *(const uint4*)(p1);       xB1 = *(const uint4*)(p1 + 16);
      xB2 = *(const uint4*)(p1 + 128); xB3 = *(const uint4*)(p1 + 144); }
    // compute chunk c from xA
    {
      v8i b0 = mkv8(xA0, xA1), b1 = mkv8(xA2, xA3);
      f32x4 acc0 = (f32x4){0.f,0.f,0.f,0.f};
      f32x4 acc1 = (f32x4){0.f,0.f,0.f,0.f};
      __builtin_amdgcn_s_setprio(1);
      acc0 = MFMA128(a[0][0], b0, acc0);
      acc1 = MFMA128(a[1][0], b0, acc1);
      acc0 = MFMA128(a[0][1], b1, acc0);
      acc1 = MFMA128(a[1][1], b1, acc1);
      __builtin_amdgcn_s_setprio(0);
      EPILOG(c, acc0, acc1);
    }
    // issue loads for chunk c+2
    if (c + 2 < 64){
      const char* p2 = bbase + (size_t)(c + 2)*4096;
      xA0 = *(const uint4*)(p2);       xA1 = *(const uint4*)(p2 + 16);
      xA2 = *(const uint4*)(p2 + 128); xA3 = *(const uint4*)(p2 + 144);
    }
    // compute chunk c+1 from xB
    {
      v8i b0 = mkv8(xB0, xB1), b1 = mkv8(xB2, xB3);
      f32x4 acc0 = (f32x4){0.f,0.f,0.f,0.f};
      f32x4 acc1 = (f32x4){0.f,0.f,0.f,0.f};
      __builtin_amdgcn_s_setprio(1);
      acc0 = MFMA128(a[0][0], b0, acc0);
      acc1 = MFMA128(a[1][0], b0, acc1);
      acc0 = MFMA128(a[0][1], b1, acc0);
      acc1 = MFMA128(a[1][1], b1, acc1);
      __builtin_amdgcn_s_setprio(0);
      EPILOG(c + 1, acc0, acc1);
    }
  }
#undef EPILOG

  // reduce over the 16 l15-lanes sharing each row
  #pragma unroll
  for (int i = 0; i < 8; ++i){
    #pragma unroll
    for (int o = 1; o < 16; o <<= 1){
      sumT[i] += __shfl_xor(sumT[i], o);
      sumO[i] += __shfl_xor(sumO[i], o);
    }
  }

  // finish in log2 domain: loss_i = ln2 * (log2(den) - pl2); ln2 folded into k_final
  float part = 0.f;
  #pragma unroll
  for (int rt = 0; rt < 2; ++rt)
    #pragma unroll
    for (int e = 0; e < 4; ++e){
      const float pl  = posLt[wid*32 + rt*16 + l4*4 + e];
      const float ep  = __builtin_amdgcn_exp2f(pl);
      const float den = ep + (sumT[rt*4+e] - sumO[rt*4+e]) + 1e-8f;
      part += __builtin_amdgcn_logf(den) - pl;   // v_log_f32 = log2
    }
  part = (l15 == 0) ? part : 0.f;
  #pragma unroll
  for (int o = 1; o < 64; o <<= 1) part += __shfl_xor(part, o);
  if (lane == 0) lossW[wid] = part;
  __syncthreads();
  if (tid == 0){
    float s = 0.f;
    #pragma unroll
    for (int i = 0; i < 8; ++i) s += lossW[i];
    atomicAdd(accum, (double)s);   // ONE atomic per block
  }
}

__global__ void k_final(const double* __restrict__ accum, float* __restrict__ out, int N){
  out[0] = (float)((*accum / (double)N) * (0.07 * 0.6931471805599453));
}

// ---------------- launch ----------------

extern "C" void kernel_launch(void* const* d_in, const int* in_sizes, int n_in,
                              void* d_out, int out_size, void* d_ws, size_t ws_size,
                              hipStream_t stream){
  const float* sp  = (const float*)d_in[0];
  const float* rp  = (const float*)d_in[1];
  const int*   idx = (const int*)d_in[2];
  const int*   lab = (const int*)d_in[3];
  const int M = in_sizes[0] / DIM;     // 1024
  const int N = in_sizes[2];           // 131072

  char* ws = (char*)d_ws;
  size_t off = 0;
  auto alloc = [&](size_t bytes){ void* p = ws + off; off = (off + bytes + 255) & ~(size_t)255; return p; };
  int*      counts  = (int*)     alloc((size_t)M * NCLS * 4);
  int*      spLabel = (int*)     alloc((size_t)M * 4);
  int*      newpos  = (int*)     alloc((size_t)M * 4);
  unsigned* packLab = (unsigned*)alloc((size_t)(M/64) * 16 * 4);
  double*   accum   = (double*)  alloc(16);
  unsigned short* spnO = (unsigned short*)alloc((size_t)M * DIM * 2);
  unsigned char*  spnP8 = (unsigned char*)alloc((size_t)M * DIM);

  k_zero<<<(M*NCLS + 255)/256, 256, 0, stream>>>(counts, packLab, accum, M*NCLS, (M/64)*16);
  k_hist<<<(N + 255)/256, 256, 0, stream>>>(idx, lab, counts, N);
  k_label_perm<<<1, M, 0, stream>>>(counts, spLabel, newpos, packLab);
  k_norm_sp<<<M, 64, 0, stream>>>(sp, newpos, spnO, spnP8);
  k_main<<<N/256, 512, 0, stream>>>(rp, idx, spnO, spnP8, packLab, spLabel, accum, M);
  k_final<<<1, 1, 0, stream>>>(accum, (float*)d_out, N);
}

// Round 18
// 102.449 us; speedup vs baseline: 1.5931x; 1.5931x over previous
//
#include <hip/hip_runtime.h>

#define NCLS 13
#define DIM  256
// (1/0.07) * log2(e): folds temperature AND exp2-domain conversion into A's scale
#define SCL  20.609929155f

typedef float f32x4 __attribute__((ext_vector_type(4)));
typedef int   v8i   __attribute__((ext_vector_type(8)));

__device__ __forceinline__ float bf2f(unsigned u16){
  union { unsigned u; float f; } v; v.u = u16 << 16; return v.f;
}
__device__ __forceinline__ unsigned f2bf(float f){
  union { float f; unsigned u; } v; v.f = f;
  unsigned r = v.u + 0x7fffu + ((v.u >> 16) & 1u);
  return r >> 16;
}
// pack 4 floats -> 4 fp8 e4m3 bytes
__device__ __forceinline__ unsigned pk4fp8(float f0, float f1, float f2, float f3){
  unsigned u = __builtin_amdgcn_cvt_pk_fp8_f32(f0, f1, 0, false);
  return (unsigned)__builtin_amdgcn_cvt_pk_fp8_f32(f2, f3, u, true);
}
__device__ __forceinline__ v8i mkv8(uint4 q0, uint4 q1){
  v8i r;
  r[0] = (int)q0.x; r[1] = (int)q0.y; r[2] = (int)q0.z; r[3] = (int)q0.w;
  r[4] = (int)q1.x; r[5] = (int)q1.y; r[6] = (int)q1.z; r[7] = (int)q1.w;
  return r;
}
// fp8 e4m3 MFMA, K=128, unit MX scales (e8m0 0x7f = 2^0) -> bit-compatible with
// non-scaled fp8 product, ~2.3x the rate, 1/4 the instruction count.
#define MFMA128(A, B, C) __builtin_amdgcn_mfma_scale_f32_16x16x128_f8f6f4( \
    (A), (B), (C), 0, 0, 0, 0x7f7f7f7f, 0, 0x7f7f7f7f)

__device__ __forceinline__ void gload_lds16(const void* g, void* l){
  __builtin_amdgcn_global_load_lds((const __attribute__((address_space(1))) unsigned*)g,
                                   (__attribute__((address_space(3))) unsigned*)l, 16, 0, 0);
}

// ---------------- prep kernels ----------------

__global__ void k_zero(int* counts, unsigned* packLab, double* accum, int n, int np){
  int i = blockIdx.x*blockDim.x + threadIdx.x;
  if (i < n)  counts[i] = 0;
  if (i < np) packLab[i] = 0u;
  if (i == 0) *accum = 0.0;
}

__global__ void k_hist(const int* __restrict__ idx, const int* __restrict__ lab,
                       int* __restrict__ counts, int n){
  int i = blockIdx.x*blockDim.x + threadIdx.x;
  if (i < n) atomicAdd(&counts[idx[i]*NCLS + lab[i]], 1);
}

// one block, M threads. argmax labels + label-sorted permutation + nibble-packed
// column labels for 64-col groups: packLab[(pos>>6)*16 + (pos&15)], nibble (pos>>4)&3.
__global__ void k_label_perm(const int* __restrict__ counts, int* __restrict__ spLabel,
                             int* __restrict__ newpos, unsigned* __restrict__ packLab){
  int m = threadIdx.x;
  int best = 0; int bc = counts[m*NCLS];
  #pragma unroll
  for (int c = 1; c < NCLS; ++c){ int v = counts[m*NCLS+c]; if (v > bc){ bc = v; best = c; } }
  spLabel[m] = best;

  __shared__ int waveCnt[16][NCLS];
  __shared__ int waveOff[16][NCLS];
  __shared__ int classTot[NCLS];
  __shared__ int classBase[NCLS];
  int lane = m & 63, wid = m >> 6;
  int nw = blockDim.x >> 6;
  int rankInWave = 0;
  unsigned long long below = (1ull << lane) - 1ull;
  for (int c = 0; c < NCLS; ++c){
    unsigned long long bal = __ballot(best == c);
    if (best == c) rankInWave = __popcll(bal & below);
    if (lane == 0) waveCnt[wid][c] = __popcll(bal);
  }
  __syncthreads();
  if (m < NCLS){
    int c = m, s = 0;
    for (int w = 0; w < nw; ++w){ waveOff[w][c] = s; s += waveCnt[w][c]; }
    classTot[c] = s;
  }
  __syncthreads();
  if (m == 0){ int s = 0; for (int c = 0; c < NCLS; ++c){ classBase[c] = s; s += classTot[c]; } }
  __syncthreads();
  int pos = classBase[best] + waveOff[wid][best] + rankInWave;
  newpos[m] = pos;
  atomicOr(&packLab[(pos >> 6)*16 + (pos & 15)], (unsigned)best << (((pos >> 4) & 3)*4));
}

// one wave per superpoint row: normalize; write spnO (bf16, linear, for pos logits)
// and spnP8 (fp8 e4m3, label-permuted row, PLAIN row-major [pos][k]).
__global__ void k_norm_sp(const float* __restrict__ sp, const int* __restrict__ newpos,
                          unsigned short* __restrict__ spnO, unsigned char* __restrict__ spnP8){
  int m = blockIdx.x, lane = threadIdx.x;
  const float4 v = *(const float4*)(sp + (size_t)m*DIM + lane*4);
  float ss = v.x*v.x + v.y*v.y + v.z*v.z + v.w*v.w;
  #pragma unroll
  for (int o = 1; o < 64; o <<= 1) ss += __shfl_xor(ss, o);
  float rn = 1.0f / sqrtf(ss + 1e-12f);
  uint2 w;
  w.x = f2bf(v.x*rn) | (f2bf(v.y*rn) << 16);
  w.y = f2bf(v.z*rn) | (f2bf(v.w*rn) << 16);
  *(uint2*)(spnO + (size_t)m*DIM + lane*4) = w;
  unsigned pk = pk4fp8(v.x*rn, v.y*rn, v.z*rn, v.w*rn);
  int p = newpos[m];
  ((unsigned*)spnP8)[p*64 + lane] = pk;     // plain: k = 4*lane..+3
}

// ---------------- main fused GEMM (MX-fp8 K=128, per-wave staging + reg b-prefetch) ----------------
// 512 threads = 8 waves; wave owns 32 rows x all 1024 cols. BM=256, grid 512,
// 2 blocks/CU = 4 waves/SIMD (R15/R16 skeleton). NEW vs R16: chunk c+1's
// b-registers are ds_read-prefetched DURING chunk c's MFMA+epilogue, removing
// the ~130cy ds_read latency from the serial chain. Buffer recycle guarded by
// lgkmcnt(0) before each stage. waves_per_eu(2,4): min=2 -> VGPR budget <=256
// (stops the occupancy-maximizing 64-reg clamp that serialized R17); max=4
// keeps 2-blocks/CU residency.

#define SBAR()   __builtin_amdgcn_s_barrier()
#define SFENCE() __builtin_amdgcn_sched_barrier(0)

__attribute__((amdgpu_waves_per_eu(2, 4)))
__launch_bounds__(512)
__global__ void k_main(const float* __restrict__ rp, const int* __restrict__ rawIdx,
                       const unsigned short* __restrict__ spnO, const unsigned char* __restrict__ spnP8,
                       const unsigned* __restrict__ packLab, const int* __restrict__ spLabel,
                       double* __restrict__ accum, int M){
  __shared__ __align__(16) char Bpriv[8*2*4096];   // 64 KB: per-wave 2x4 KB (A staging overlay)
  __shared__ float    posLt[256];
  __shared__ int      posLb[256];
  __shared__ unsigned cpLds[256];
  __shared__ float    lossW[8];

  const int tid  = threadIdx.x;
  const int lane = tid & 63, wid = tid >> 6;
  const int l15  = lane & 15, l4 = lane >> 4;
  const int rowBlock = blockIdx.x * 256;
  char* wb = Bpriv + wid*8192;                     // this wave's 2 buffers

  if (tid < 256) cpLds[tid] = packLab[tid];
  if (lane < 32){
    int r = wid*32 + lane;
    posLb[r] = spLabel[rawIdx[rowBlock + r]];
  }

  // ---- prologue: normalize 32 rows/wave -> fp8 into wave-private LDS slots ----
  v8i a[2][2];   // [row-tile p][K-half h]
  #pragma unroll
  for (int p = 0; p < 2; ++p){
    for (int it = 0; it < 4; ++it){
      const int rl = p*16 + it*4 + l4;             // wave-local row (= slot)
      const int t  = l15;
      const float* rpp = rp + (size_t)(rowBlock + wid*32 + rl)*DIM + t*16;
      const float4 v0 = *(const float4*)(rpp);
      const float4 v1 = *(const float4*)(rpp + 4);
      const float4 v2 = *(const float4*)(rpp + 8);
      const float4 v3 = *(const float4*)(rpp + 12);
      float ss = v0.x*v0.x + v0.y*v0.y + v0.z*v0.z + v0.w*v0.w
               + v1.x*v1.x + v1.y*v1.y + v1.z*v1.z + v1.w*v1.w
               + v2.x*v2.x + v2.y*v2.y + v2.z*v2.z + v2.w*v2.w
               + v3.x*v3.x + v3.y*v3.y + v3.z*v3.z + v3.w*v3.w;
      const int sidx = rawIdx[rowBlock + wid*32 + rl];
      const uint4 s0 = *(const uint4*)(spnO + (size_t)sidx*DIM + t*16);
      const uint4 s1 = *(const uint4*)(spnO + (size_t)sidx*DIM + t*16 + 8);
      float dr =
        v0.x*bf2f(s0.x & 0xffff) + v0.y*bf2f(s0.x >> 16) +
        v0.z*bf2f(s0.y & 0xffff) + v0.w*bf2f(s0.y >> 16) +
        v1.x*bf2f(s0.z & 0xffff) + v1.y*bf2f(s0.z >> 16) +
        v1.z*bf2f(s0.w & 0xffff) + v1.w*bf2f(s0.w >> 16) +
        v2.x*bf2f(s1.x & 0xffff) + v2.y*bf2f(s1.x >> 16) +
        v2.z*bf2f(s1.y & 0xffff) + v2.w*bf2f(s1.y >> 16) +
        v3.x*bf2f(s1.z & 0xffff) + v3.y*bf2f(s1.z >> 16) +
        v3.z*bf2f(s1.w & 0xffff) + v3.w*bf2f(s1.w >> 16);
      ss += __shfl_xor(ss, 1); dr += __shfl_xor(dr, 1);
      ss += __shfl_xor(ss, 2); dr += __shfl_xor(dr, 2);
      ss += __shfl_xor(ss, 4); dr += __shfl_xor(dr, 4);
      ss += __shfl_xor(ss, 8); dr += __shfl_xor(dr, 8);
      const float rn = SCL / sqrtf(ss + 1e-12f);
      const int slot = rl;
      const int swz  = (slot & 7) << 4;
      uint4 h;
      h.x = pk4fp8(v0.x*rn, v0.y*rn, v0.z*rn, v0.w*rn);
      h.y = pk4fp8(v1.x*rn, v1.y*rn, v1.z*rn, v1.w*rn);
      h.z = pk4fp8(v2.x*rn, v2.y*rn, v2.z*rn, v2.w*rn);
      h.w = pk4fp8(v3.x*rn, v3.y*rn, v3.z*rn, v3.w*rn);
      *(uint4*)(wb + slot*256 + ((t*16) ^ swz)) = h;   // plain k [t*16,+16) -> swz image
      if (l15 == 0) posLt[wid*32 + rl] = rn * dr;
    }
    // frag reads: slots written by THIS wave (same-wave LDS ordering)
    #pragma unroll
    for (int h = 0; h < 2; ++h){
      const int s   = p*16 + l15;
      const int swz = (l15 & 7) << 4;
      const int off = (h*128 + l4*32) ^ swz;
      uint4 q0 = *(const uint4*)(wb + s*256 + off);
      uint4 q1 = *(const uint4*)(wb + s*256 + (off ^ 16));
      a[p][h] = mkv8(q0, q1);
    }
  }

  // row labels nibble-packed: ri = rt*4+e -> wave-local row rt*16 + l4*4 + e
  unsigned Lpack = 0;
  #pragma unroll
  for (int rt = 0; rt < 2; ++rt)
    #pragma unroll
    for (int e = 0; e < 4; ++e)
      Lpack |= ((unsigned)posLb[wid*32 + rt*16 + l4*4 + e]) << ((rt*4 + e)*4);

  float sumT[8], sumO[8];
  #pragma unroll
  for (int i = 0; i < 8; ++i){ sumT[i] = 0.f; sumO[i] = 0.f; }

  // per-lane staging source bases: chunk c, col j -> bs[j] + c*4096
  const unsigned char* bs[4];
  #pragma unroll
  for (int j = 0; j < 4; ++j){
    const int colb = j*4 + l4;
    bs[j] = spnP8 + (size_t)colb*256 + ((l15 ^ (colb & 7)) << 4);
  }

  // all A-frag ds_reads landed before buffers get recycled (rule #18)
  asm volatile("s_waitcnt lgkmcnt(0)" ::: "memory");
  SFENCE();
  #pragma unroll
  for (int j = 0; j < 4; ++j) gload_lds16(bs[j],        wb        + j*1024);  // chunk 0
  #pragma unroll
  for (int j = 0; j < 4; ++j) gload_lds16(bs[j] + 4096, wb + 4096 + j*1024);  // chunk 1
  SBAR();                                  // cpLds visible (raw: keeps vmcnt)
  asm volatile("s_waitcnt vmcnt(4)" ::: "memory");   // chunk 0 landed
  SFENCE();

  // preload chunk 0 b-registers
  const int swzr = (l15 & 7) << 4;
  const int o0 = (l4*32) ^ swzr;
  const int o1 = (128 + l4*32) ^ swzr;
  uint4 c0, c1, c2, c3, n0, n1, n2, n3;
  { const char* bp = wb + l15*256;
    c0 = *(const uint4*)(bp + o0); c1 = *(const uint4*)(bp + (o0 ^ 16));
    c2 = *(const uint4*)(bp + o1); c3 = *(const uint4*)(bp + (o1 ^ 16)); }

  // ---- K loop: 64 chunks, per-wave depth-2 staging + reg b-prefetch, NO barriers ----
  for (int c = 0; c < 64; ++c){
    char* bufc = wb + (c & 1)*4096;
    // drain reads of bufc's old content (now in rolled regs), then recycle it
    asm volatile("s_waitcnt lgkmcnt(0)" ::: "memory");
    SFENCE();
    if (c + 2 < 64){
      const size_t off = (size_t)(c + 2)*4096;
      #pragma unroll
      for (int j = 0; j < 4; ++j) gload_lds16(bs[j] + off, bufc + j*1024);
    }
    // prefetch chunk c+1's b-regs (latency hides under MFMA+epilogue below)
    if (c + 1 < 64){
      if (c + 2 < 64) asm volatile("s_waitcnt vmcnt(4)" ::: "memory");
      else            asm volatile("s_waitcnt vmcnt(0)" ::: "memory");
      SFENCE();
      const char* bp = wb + ((c + 1) & 1)*4096 + l15*256;
      n0 = *(const uint4*)(bp + o0); n1 = *(const uint4*)(bp + (o0 ^ 16));
      n2 = *(const uint4*)(bp + o1); n3 = *(const uint4*)(bp + (o1 ^ 16));
    }

    v8i b0 = mkv8(c0, c1), b1 = mkv8(c2, c3);
    f32x4 acc0 = (f32x4){0.f,0.f,0.f,0.f};
    f32x4 acc1 = (f32x4){0.f,0.f,0.f,0.f};
    __builtin_amdgcn_s_setprio(1);
    acc0 = MFMA128(a[0][0], b0, acc0);
    acc1 = MFMA128(a[1][0], b0, acc1);
    acc0 = MFMA128(a[0][1], b1, acc0);
    acc1 = MFMA128(a[1][1], b1, acc1);
    __builtin_amdgcn_s_setprio(0);

    const unsigned colLab = (cpLds[(c >> 2)*16 + l15] >> ((c & 3)*4)) & 15u;
    #pragma unroll
    for (int e = 0; e < 4; ++e){
      const float ev0 = __builtin_amdgcn_exp2f(acc0[e]);
      const float ev1 = __builtin_amdgcn_exp2f(acc1[e]);
      sumT[e]   += ev0;
      sumT[4+e] += ev1;
      sumO[e]   += (((Lpack >> (e*4)) & 15u)     == colLab) ? ev0 : 0.f;
      sumO[4+e] += (((Lpack >> ((4+e)*4)) & 15u) == colLab) ? ev1 : 0.f;
    }
    c0 = n0; c1 = n1; c2 = n2; c3 = n3;
  }

  // reduce over the 16 l15-lanes sharing each row
  #pragma unroll
  for (int i = 0; i < 8; ++i){
    #pragma unroll
    for (int o = 1; o < 16; o <<= 1){
      sumT[i] += __shfl_xor(sumT[i], o);
      sumO[i] += __shfl_xor(sumO[i], o);
    }
  }

  // finish in log2 domain: loss_i = ln2 * (log2(den) - pl2); ln2 folded into k_final
  float part = 0.f;
  #pragma unroll
  for (int rt = 0; rt < 2; ++rt)
    #pragma unroll
    for (int e = 0; e < 4; ++e){
      const float pl  = posLt[wid*32 + rt*16 + l4*4 + e];
      const float ep  = __builtin_amdgcn_exp2f(pl);
      const float den = ep + (sumT[rt*4+e] - sumO[rt*4+e]) + 1e-8f;
      part += __builtin_amdgcn_logf(den) - pl;   // v_log_f32 = log2
    }
  part = (l15 == 0) ? part : 0.f;
  #pragma unroll
  for (int o = 1; o < 64; o <<= 1) part += __shfl_xor(part, o);
  if (lane == 0) lossW[wid] = part;
  __syncthreads();
  if (tid == 0){
    float s = 0.f;
    #pragma unroll
    for (int i = 0; i < 8; ++i) s += lossW[i];
    atomicAdd(accum, (double)s);   // ONE atomic per block
  }
}

__global__ void k_final(const double* __restrict__ accum, float* __restrict__ out, int N){
  out[0] = (float)((*accum / (double)N) * (0.07 * 0.6931471805599453));
}

// ---------------- launch ----------------

extern "C" void kernel_launch(void* const* d_in, const int* in_sizes, int n_in,
                              void* d_out, int out_size, void* d_ws, size_t ws_size,
                              hipStream_t stream){
  const float* sp  = (const float*)d_in[0];
  const float* rp  = (const float*)d_in[1];
  const int*   idx = (const int*)d_in[2];
  const int*   lab = (const int*)d_in[3];
  const int M = in_sizes[0] / DIM;     // 1024
  const int N = in_sizes[2];           // 131072

  char* ws = (char*)d_ws;
  size_t off = 0;
  auto alloc = [&](size_t bytes){ void* p = ws + off; off = (off + bytes + 255) & ~(size_t)255; return p; };
  int*      counts  = (int*)     alloc((size_t)M * NCLS * 4);
  int*      spLabel = (int*)     alloc((size_t)M * 4);
  int*      newpos  = (int*)     alloc((size_t)M * 4);
  unsigned* packLab = (unsigned*)alloc((size_t)(M/64) * 16 * 4);
  double*   accum   = (double*)  alloc(16);
  unsigned short* spnO = (unsigned short*)alloc((size_t)M * DIM * 2);
  unsigned char*  spnP8 = (unsigned char*)alloc((size_t)M * DIM);

  k_zero<<<(M*NCLS + 255)/256, 256, 0, stream>>>(counts, packLab, accum, M*NCLS, (M/64)*16);
  k_hist<<<(N + 255)/256, 256, 0, stream>>>(idx, lab, counts, N);
  k_label_perm<<<1, M, 0, stream>>>(counts, spLabel, newpos, packLab);
  k_norm_sp<<<M, 64, 0, stream>>>(sp, newpos, spnO, spnP8);
  k_main<<<N/256, 512, 0, stream>>>(rp, idx, spnO, spnP8, packLab, spLabel, accum, M);
  k_final<<<1, 1, 0, stream>>>(accum, (float*)d_out, N);
}

// Round 19
// 99.133 us; speedup vs baseline: 1.6464x; 1.0335x over previous
//
#include <hip/hip_runtime.h>

#define NCLS 13
#define DIM  256
// (1/0.07) * log2(e): folds temperature AND exp2-domain conversion into A's scale
#define SCL  20.609929155f

typedef float f32x4 __attribute__((ext_vector_type(4)));
typedef int   v8i   __attribute__((ext_vector_type(8)));

__device__ __forceinline__ float bf2f(unsigned u16){
  union { unsigned u; float f; } v; v.u = u16 << 16; return v.f;
}
__device__ __forceinline__ unsigned f2bf(float f){
  union { float f; unsigned u; } v; v.f = f;
  unsigned r = v.u + 0x7fffu + ((v.u >> 16) & 1u);
  return r >> 16;
}
// pack 4 floats -> 4 fp8 e4m3 bytes
__device__ __forceinline__ unsigned pk4fp8(float f0, float f1, float f2, float f3){
  unsigned u = __builtin_amdgcn_cvt_pk_fp8_f32(f0, f1, 0, false);
  return (unsigned)__builtin_amdgcn_cvt_pk_fp8_f32(f2, f3, u, true);
}
__device__ __forceinline__ v8i mkv8(uint4 q0, uint4 q1){
  v8i r;
  r[0] = (int)q0.x; r[1] = (int)q0.y; r[2] = (int)q0.z; r[3] = (int)q0.w;
  r[4] = (int)q1.x; r[5] = (int)q1.y; r[6] = (int)q1.z; r[7] = (int)q1.w;
  return r;
}
// fp8 e4m3 MFMA, K=128, unit MX scales (e8m0 0x7f = 2^0) -> bit-compatible with
// non-scaled fp8 product, ~2.3x the rate, 1/4 the instruction count.
#define MFMA128(A, B, C) __builtin_amdgcn_mfma_scale_f32_16x16x128_f8f6f4( \
    (A), (B), (C), 0, 0, 0, 0x7f7f7f7f, 0, 0x7f7f7f7f)

__device__ __forceinline__ void gload_lds16(const void* g, void* l){
  __builtin_amdgcn_global_load_lds((const __attribute__((address_space(1))) unsigned*)g,
                                   (__attribute__((address_space(3))) unsigned*)l, 16, 0, 0);
}

// ---------------- prep kernels ----------------

__global__ void k_zero(int* counts, unsigned* packLab, double* accum, int n, int np){
  int i = blockIdx.x*blockDim.x + threadIdx.x;
  if (i < n)  counts[i] = 0;
  if (i < np) packLab[i] = 0u;
  if (i == 0) *accum = 0.0;
}

__global__ void k_hist(const int* __restrict__ idx, const int* __restrict__ lab,
                       int* __restrict__ counts, int n){
  int i = blockIdx.x*blockDim.x + threadIdx.x;
  if (i < n) atomicAdd(&counts[idx[i]*NCLS + lab[i]], 1);
}

// one block, M threads. argmax labels + label-sorted permutation + nibble-packed
// column labels for 64-col groups: packLab[(pos>>6)*16 + (pos&15)], nibble (pos>>4)&3.
__global__ void k_label_perm(const int* __restrict__ counts, int* __restrict__ spLabel,
                             int* __restrict__ newpos, unsigned* __restrict__ packLab){
  int m = threadIdx.x;
  int best = 0; int bc = counts[m*NCLS];
  #pragma unroll
  for (int c = 1; c < NCLS; ++c){ int v = counts[m*NCLS+c]; if (v > bc){ bc = v; best = c; } }
  spLabel[m] = best;

  __shared__ int waveCnt[16][NCLS];
  __shared__ int waveOff[16][NCLS];
  __shared__ int classTot[NCLS];
  __shared__ int classBase[NCLS];
  int lane = m & 63, wid = m >> 6;
  int nw = blockDim.x >> 6;
  int rankInWave = 0;
  unsigned long long below = (1ull << lane) - 1ull;
  for (int c = 0; c < NCLS; ++c){
    unsigned long long bal = __ballot(best == c);
    if (best == c) rankInWave = __popcll(bal & below);
    if (lane == 0) waveCnt[wid][c] = __popcll(bal);
  }
  __syncthreads();
  if (m < NCLS){
    int c = m, s = 0;
    for (int w = 0; w < nw; ++w){ waveOff[w][c] = s; s += waveCnt[w][c]; }
    classTot[c] = s;
  }
  __syncthreads();
  if (m == 0){ int s = 0; for (int c = 0; c < NCLS; ++c){ classBase[c] = s; s += classTot[c]; } }
  __syncthreads();
  int pos = classBase[best] + waveOff[wid][best] + rankInWave;
  newpos[m] = pos;
  atomicOr(&packLab[(pos >> 6)*16 + (pos & 15)], (unsigned)best << (((pos >> 4) & 3)*4));
}

// one wave per superpoint row: normalize; write spnO (bf16, linear, for pos logits)
// and spnP8 (fp8 e4m3, label-permuted row, PLAIN row-major [pos][k]).
__global__ void k_norm_sp(const float* __restrict__ sp, const int* __restrict__ newpos,
                          unsigned short* __restrict__ spnO, unsigned char* __restrict__ spnP8){
  int m = blockIdx.x, lane = threadIdx.x;
  const float4 v = *(const float4*)(sp + (size_t)m*DIM + lane*4);
  float ss = v.x*v.x + v.y*v.y + v.z*v.z + v.w*v.w;
  #pragma unroll
  for (int o = 1; o < 64; o <<= 1) ss += __shfl_xor(ss, o);
  float rn = 1.0f / sqrtf(ss + 1e-12f);
  uint2 w;
  w.x = f2bf(v.x*rn) | (f2bf(v.y*rn) << 16);
  w.y = f2bf(v.z*rn) | (f2bf(v.w*rn) << 16);
  *(uint2*)(spnO + (size_t)m*DIM + lane*4) = w;
  unsigned pk = pk4fp8(v.x*rn, v.y*rn, v.z*rn, v.w*rn);
  int p = newpos[m];
  ((unsigned*)spnP8)[p*64 + lane] = pk;     // plain: k = 4*lane..+3
}

// ---------------- main fused GEMM (MX-fp8 K=128, per-wave-private pipelined staging) ----------------
// R16 champion schedule, two micro-cleanups: (1) ds_read lands DIRECTLY in the
// MFMA's v8i register tuples (kills ~16 v_mov repack per chunk); (2) cpLds
// column-label word hoisted once per 4 chunks. Everything else identical:
// 512 thr = 8 waves, wave owns 32 rows x 1024 cols, per-wave 2x4KB private
// B-buffers, counted vmcnt(4), no in-loop barriers, 2 blocks/CU.

#define SBAR()   __builtin_amdgcn_s_barrier()
#define SFENCE() __builtin_amdgcn_sched_barrier(0)

__attribute__((amdgpu_waves_per_eu(1, 4)))
__launch_bounds__(512)
__global__ void k_main(const float* __restrict__ rp, const int* __restrict__ rawIdx,
                       const unsigned short* __restrict__ spnO, const unsigned char* __restrict__ spnP8,
                       const unsigned* __restrict__ packLab, const int* __restrict__ spLabel,
                       double* __restrict__ accum, int M){
  __shared__ __align__(16) char Bpriv[8*2*4096];   // 64 KB: per-wave 2x4 KB
  __shared__ float    posLt[256];
  __shared__ int      posLb[256];
  __shared__ unsigned cpLds[256];
  __shared__ float    lossW[8];

  const int tid  = threadIdx.x;
  const int lane = tid & 63, wid = tid >> 6;
  const int l15  = lane & 15, l4 = lane >> 4;
  const int rowBlock = blockIdx.x * 256;
  char* wb = Bpriv + wid*8192;                     // this wave's 2 buffers

  if (tid < 256) cpLds[tid] = packLab[tid];
  if (lane < 32){
    int r = wid*32 + lane;
    posLb[r] = spLabel[rawIdx[rowBlock + r]];
  }

  // ---- prologue: normalize 32 rows/wave -> fp8 into wave-private LDS slots ----
  v8i a[2][2];   // [row-tile p][K-half h]
  #pragma unroll
  for (int p = 0; p < 2; ++p){
    for (int it = 0; it < 4; ++it){
      const int rl = p*16 + it*4 + l4;             // wave-local row (= slot)
      const int t  = l15;
      const float* rpp = rp + (size_t)(rowBlock + wid*32 + rl)*DIM + t*16;
      const float4 v0 = *(const float4*)(rpp);
      const float4 v1 = *(const float4*)(rpp + 4);
      const float4 v2 = *(const float4*)(rpp + 8);
      const float4 v3 = *(const float4*)(rpp + 12);
      float ss = v0.x*v0.x + v0.y*v0.y + v0.z*v0.z + v0.w*v0.w
               + v1.x*v1.x + v1.y*v1.y + v1.z*v1.z + v1.w*v1.w
               + v2.x*v2.x + v2.y*v2.y + v2.z*v2.z + v2.w*v2.w
               + v3.x*v3.x + v3.y*v3.y + v3.z*v3.z + v3.w*v3.w;
      const int sidx = rawIdx[rowBlock + wid*32 + rl];
      const uint4 s0 = *(const uint4*)(spnO + (size_t)sidx*DIM + t*16);
      const uint4 s1 = *(const uint4*)(spnO + (size_t)sidx*DIM + t*16 + 8);
      float dr =
        v0.x*bf2f(s0.x & 0xffff) + v0.y*bf2f(s0.x >> 16) +
        v0.z*bf2f(s0.y & 0xffff) + v0.w*bf2f(s0.y >> 16) +
        v1.x*bf2f(s0.z & 0xffff) + v1.y*bf2f(s0.z >> 16) +
        v1.z*bf2f(s0.w & 0xffff) + v1.w*bf2f(s0.w >> 16) +
        v2.x*bf2f(s1.x & 0xffff) + v2.y*bf2f(s1.x >> 16) +
        v2.z*bf2f(s1.y & 0xffff) + v2.w*bf2f(s1.y >> 16) +
        v3.x*bf2f(s1.z & 0xffff) + v3.y*bf2f(s1.z >> 16) +
        v3.z*bf2f(s1.w & 0xffff) + v3.w*bf2f(s1.w >> 16);
      ss += __shfl_xor(ss, 1); dr += __shfl_xor(dr, 1);
      ss += __shfl_xor(ss, 2); dr += __shfl_xor(dr, 2);
      ss += __shfl_xor(ss, 4); dr += __shfl_xor(dr, 4);
      ss += __shfl_xor(ss, 8); dr += __shfl_xor(dr, 8);
      const float rn = SCL / sqrtf(ss + 1e-12f);
      const int slot = rl;
      const int swz  = (slot & 7) << 4;
      uint4 h;
      h.x = pk4fp8(v0.x*rn, v0.y*rn, v0.z*rn, v0.w*rn);
      h.y = pk4fp8(v1.x*rn, v1.y*rn, v1.z*rn, v1.w*rn);
      h.z = pk4fp8(v2.x*rn, v2.y*rn, v2.z*rn, v2.w*rn);
      h.w = pk4fp8(v3.x*rn, v3.y*rn, v3.z*rn, v3.w*rn);
      *(uint4*)(wb + slot*256 + ((t*16) ^ swz)) = h;   // plain k [t*16,+16) -> swz image
      if (l15 == 0) posLt[wid*32 + rl] = rn * dr;
    }
    // frag reads: slots written by THIS wave (same-wave LDS ordering)
    #pragma unroll
    for (int h = 0; h < 2; ++h){
      const int s   = p*16 + l15;
      const int swz = (l15 & 7) << 4;
      const int off = (h*128 + l4*32) ^ swz;
      uint4 q0 = *(const uint4*)(wb + s*256 + off);
      uint4 q1 = *(const uint4*)(wb + s*256 + (off ^ 16));
      a[p][h] = mkv8(q0, q1);
    }
  }

  // row labels nibble-packed: ri = rt*4+e -> wave-local row rt*16 + l4*4 + e
  unsigned Lpack = 0;
  #pragma unroll
  for (int rt = 0; rt < 2; ++rt)
    #pragma unroll
    for (int e = 0; e < 4; ++e)
      Lpack |= ((unsigned)posLb[wid*32 + rt*16 + l4*4 + e]) << ((rt*4 + e)*4);

  float sumT[8], sumO[8];
  #pragma unroll
  for (int i = 0; i < 8; ++i){ sumT[i] = 0.f; sumO[i] = 0.f; }

  // per-lane staging source bases: chunk c, col j -> bs[j] + c*4096
  const unsigned char* bs[4];
  #pragma unroll
  for (int j = 0; j < 4; ++j){
    const int colb = j*4 + l4;
    bs[j] = spnP8 + (size_t)colb*256 + ((l15 ^ (colb & 7)) << 4);
  }

  // all A-frag ds_reads landed before buffers get recycled (rule #18)
  asm volatile("s_waitcnt lgkmcnt(0)" ::: "memory");
  SFENCE();
  #pragma unroll
  for (int j = 0; j < 4; ++j) gload_lds16(bs[j],        wb        + j*1024);  // chunk 0
  #pragma unroll
  for (int j = 0; j < 4; ++j) gload_lds16(bs[j] + 4096, wb + 4096 + j*1024);  // chunk 1
  SBAR();                                  // cpLds visible (raw: keeps vmcnt)

  const int swzr = (l15 & 7) << 4;
  const int o0 = (l4*32) ^ swzr;
  const int o1 = (128 + l4*32) ^ swzr;

  // ---- K loop: 16 quads x 4 chunks, per-wave depth-2 pipeline, NO barriers ----
  for (int cq = 0; cq < 16; ++cq){
    const unsigned cpack = cpLds[cq*16 + l15];
    #pragma unroll
    for (int ci = 0; ci < 4; ++ci){
      const int c = cq*4 + ci;
      if (c < 63) asm volatile("s_waitcnt vmcnt(4)" ::: "memory");  // chunk c landed
      else        asm volatile("s_waitcnt vmcnt(0)" ::: "memory");
      SFENCE();
      char* buf = wb + (c & 1)*4096;
      const char* bp = buf + l15*256;
      // ds_read lands DIRECTLY in the MFMA operand tuples (no repack movs)
      v8i b0, b1;
      {
        uint4* pb0 = (uint4*)&b0;
        pb0[0] = *(const uint4*)(bp + o0);
        pb0[1] = *(const uint4*)(bp + (o0 ^ 16));
        uint4* pb1 = (uint4*)&b1;
        pb1[0] = *(const uint4*)(bp + o1);
        pb1[1] = *(const uint4*)(bp + (o1 ^ 16));
      }
      asm volatile("s_waitcnt lgkmcnt(0)" ::: "memory");   // b landed before overwrite
      SFENCE();
      if (c + 2 < 64){
        const size_t off = (size_t)(c + 2)*4096;
        #pragma unroll
        for (int j = 0; j < 4; ++j) gload_lds16(bs[j] + off, buf + j*1024);
      }

      f32x4 acc0 = (f32x4){0.f,0.f,0.f,0.f};
      f32x4 acc1 = (f32x4){0.f,0.f,0.f,0.f};
      __builtin_amdgcn_s_setprio(1);
      acc0 = MFMA128(a[0][0], b0, acc0);
      acc1 = MFMA128(a[1][0], b0, acc1);
      acc0 = MFMA128(a[0][1], b1, acc0);
      acc1 = MFMA128(a[1][1], b1, acc1);
      __builtin_amdgcn_s_setprio(0);

      const unsigned colLab = (cpack >> (ci*4)) & 15u;
      #pragma unroll
      for (int e = 0; e < 4; ++e){
        const float ev0 = __builtin_amdgcn_exp2f(acc0[e]);
        const float ev1 = __builtin_amdgcn_exp2f(acc1[e]);
        sumT[e]   += ev0;
        sumT[4+e] += ev1;
        sumO[e]   += (((Lpack >> (e*4)) & 15u)     == colLab) ? ev0 : 0.f;
        sumO[4+e] += (((Lpack >> ((4+e)*4)) & 15u) == colLab) ? ev1 : 0.f;
      }
    }
  }

  // reduce over the 16 l15-lanes sharing each row
  #pragma unroll
  for (int i = 0; i < 8; ++i){
    #pragma unroll
    for (int o = 1; o < 16; o <<= 1){
      sumT[i] += __shfl_xor(sumT[i], o);
      sumO[i] += __shfl_xor(sumO[i], o);
    }
  }

  // finish in log2 domain: loss_i = ln2 * (log2(den) - pl2); ln2 folded into k_final
  float part = 0.f;
  #pragma unroll
  for (int rt = 0; rt < 2; ++rt)
    #pragma unroll
    for (int e = 0; e < 4; ++e){
      const float pl  = posLt[wid*32 + rt*16 + l4*4 + e];
      const float ep  = __builtin_amdgcn_exp2f(pl);
      const float den = ep + (sumT[rt*4+e] - sumO[rt*4+e]) + 1e-8f;
      part += __builtin_amdgcn_logf(den) - pl;   // v_log_f32 = log2
    }
  part = (l15 == 0) ? part : 0.f;
  #pragma unroll
  for (int o = 1; o < 64; o <<= 1) part += __shfl_xor(part, o);
  if (lane == 0) lossW[wid] = part;
  __syncthreads();
  if (tid == 0){
    float s = 0.f;
    #pragma unroll
    for (int i = 0; i < 8; ++i) s += lossW[i];
    atomicAdd(accum, (double)s);   // ONE atomic per block
  }
}

__global__ void k_final(const double* __restrict__ accum, float* __restrict__ out, int N){
  out[0] = (float)((*accum / (double)N) * (0.07 * 0.6931471805599453));
}

// ---------------- launch ----------------

extern "C" void kernel_launch(void* const* d_in, const int* in_sizes, int n_in,
                              void* d_out, int out_size, void* d_ws, size_t ws_size,
                              hipStream_t stream){
  const float* sp  = (const float*)d_in[0];
  const float* rp  = (const float*)d_in[1];
  const int*   idx = (const int*)d_in[2];
  const int*   lab = (const int*)d_in[3];
  const int M = in_sizes[0] / DIM;     // 1024
  const int N = in_sizes[2];           // 131072

  char* ws = (char*)d_ws;
  size_t off = 0;
  auto alloc = [&](size_t bytes){ void* p = ws + off; off = (off + bytes + 255) & ~(size_t)255; return p; };
  int*      counts  = (int*)     alloc((size_t)M * NCLS * 4);
  int*      spLabel = (int*)     alloc((size_t)M * 4);
  int*      newpos  = (int*)     alloc((size_t)M * 4);
  unsigned* packLab = (unsigned*)alloc((size_t)(M/64) * 16 * 4);
  double*   accum   = (double*)  alloc(16);
  unsigned short* spnO = (unsigned short*)alloc((size_t)M * DIM * 2);
  unsigned char*  spnP8 = (unsigned char*)alloc((size_t)M * DIM);

  k_zero<<<(M*NCLS + 255)/256, 256, 0, stream>>>(counts, packLab, accum, M*NCLS, (M/64)*16);
  k_hist<<<(N + 255)/256, 256, 0, stream>>>(idx, lab, counts, N);
  k_label_perm<<<1, M, 0, stream>>>(counts, spLabel, newpos, packLab);
  k_norm_sp<<<M, 64, 0, stream>>>(sp, newpos, spnO, spnP8);
  k_main<<<N/256, 512, 0, stream>>>(rp, idx, spnO, spnP8, packLab, spLabel, accum, M);
  k_final<<<1, 1, 0, stream>>>(accum, (float*)d_out, N);
}

// Round 20
// 90.862 us; speedup vs baseline: 1.7962x; 1.0910x over previous
//
#include <hip/hip_runtime.h>

#define NCLS 13
#define DIM  256
// (1/0.07) * log2(e): folds temperature AND exp2-domain conversion into A's scale
#define SCL  20.609929155f

typedef float f32x4 __attribute__((ext_vector_type(4)));
typedef int   v8i   __attribute__((ext_vector_type(8)));

__device__ __forceinline__ float bf2f(unsigned u16){
  union { unsigned u; float f; } v; v.u = u16 << 16; return v.f;
}
__device__ __forceinline__ unsigned f2bf(float f){
  union { float f; unsigned u; } v; v.f = f;
  unsigned r = v.u + 0x7fffu + ((v.u >> 16) & 1u);
  return r >> 16;
}
// pack 4 floats -> 4 fp8 e4m3 bytes
__device__ __forceinline__ unsigned pk4fp8(float f0, float f1, float f2, float f3){
  unsigned u = __builtin_amdgcn_cvt_pk_fp8_f32(f0, f1, 0, false);
  return (unsigned)__builtin_amdgcn_cvt_pk_fp8_f32(f2, f3, u, true);
}
__device__ __forceinline__ v8i mkv8(uint4 q0, uint4 q1){
  v8i r;
  r[0] = (int)q0.x; r[1] = (int)q0.y; r[2] = (int)q0.z; r[3] = (int)q0.w;
  r[4] = (int)q1.x; r[5] = (int)q1.y; r[6] = (int)q1.z; r[7] = (int)q1.w;
  return r;
}
// fp8 e4m3 MFMA, K=128, unit MX scales (e8m0 0x7f = 2^0) -> bit-compatible with
// non-scaled fp8 product, ~2.3x the rate, 1/4 the instruction count.
#define MFMA128(A, B, C) __builtin_amdgcn_mfma_scale_f32_16x16x128_f8f6f4( \
    (A), (B), (C), 0, 0, 0, 0x7f7f7f7f, 0, 0x7f7f7f7f)

__device__ __forceinline__ void gload_lds16(const void* g, void* l){
  __builtin_amdgcn_global_load_lds((const __attribute__((address_space(1))) unsigned*)g,
                                   (__attribute__((address_space(3))) unsigned*)l, 16, 0, 0);
}

// ---------------- prep kernels ----------------

__global__ void k_zero(int* counts, unsigned* packLab, double* accum, int n, int np){
  int i = blockIdx.x*blockDim.x + threadIdx.x;
  if (i < n)  counts[i] = 0;
  if (i < np) packLab[i] = 0u;
  if (i == 0) *accum = 0.0;
}

__global__ void k_hist(const int* __restrict__ idx, const int* __restrict__ lab,
                       int* __restrict__ counts, int n){
  int i = blockIdx.x*blockDim.x + threadIdx.x;
  if (i < n) atomicAdd(&counts[idx[i]*NCLS + lab[i]], 1);
}

// one block, M threads. argmax labels + label-sorted permutation + nibble-packed
// column labels for 64-col groups: packLab[(pos>>6)*16 + (pos&15)], nibble (pos>>4)&3.
__global__ void k_label_perm(const int* __restrict__ counts, int* __restrict__ spLabel,
                             int* __restrict__ newpos, unsigned* __restrict__ packLab){
  int m = threadIdx.x;
  int best = 0; int bc = counts[m*NCLS];
  #pragma unroll
  for (int c = 1; c < NCLS; ++c){ int v = counts[m*NCLS+c]; if (v > bc){ bc = v; best = c; } }
  spLabel[m] = best;

  __shared__ int waveCnt[16][NCLS];
  __shared__ int waveOff[16][NCLS];
  __shared__ int classTot[NCLS];
  __shared__ int classBase[NCLS];
  int lane = m & 63, wid = m >> 6;
  int nw = blockDim.x >> 6;
  int rankInWave = 0;
  unsigned long long below = (1ull << lane) - 1ull;
  for (int c = 0; c < NCLS; ++c){
    unsigned long long bal = __ballot(best == c);
    if (best == c) rankInWave = __popcll(bal & below);
    if (lane == 0) waveCnt[wid][c] = __popcll(bal);
  }
  __syncthreads();
  if (m < NCLS){
    int c = m, s = 0;
    for (int w = 0; w < nw; ++w){ waveOff[w][c] = s; s += waveCnt[w][c]; }
    classTot[c] = s;
  }
  __syncthreads();
  if (m == 0){ int s = 0; for (int c = 0; c < NCLS; ++c){ classBase[c] = s; s += classTot[c]; } }
  __syncthreads();
  int pos = classBase[best] + waveOff[wid][best] + rankInWave;
  newpos[m] = pos;
  atomicOr(&packLab[(pos >> 6)*16 + (pos & 15)], (unsigned)best << (((pos >> 4) & 3)*4));
}

// one wave per superpoint row: normalize; write spnO (bf16, linear, for pos logits)
// and spnP8 (fp8 e4m3, label-permuted row, PLAIN row-major [pos][k]).
__global__ void k_norm_sp(const float* __restrict__ sp, const int* __restrict__ newpos,
                          unsigned short* __restrict__ spnO, unsigned char* __restrict__ spnP8){
  int m = blockIdx.x, lane = threadIdx.x;
  const float4 v = *(const float4*)(sp + (size_t)m*DIM + lane*4);
  float ss = v.x*v.x + v.y*v.y + v.z*v.z + v.w*v.w;
  #pragma unroll
  for (int o = 1; o < 64; o <<= 1) ss += __shfl_xor(ss, o);
  float rn = 1.0f / sqrtf(ss + 1e-12f);
  uint2 w;
  w.x = f2bf(v.x*rn) | (f2bf(v.y*rn) << 16);
  w.y = f2bf(v.z*rn) | (f2bf(v.w*rn) << 16);
  *(uint2*)(spnO + (size_t)m*DIM + lane*4) = w;
  unsigned pk = pk4fp8(v.x*rn, v.y*rn, v.z*rn, v.w*rn);
  int p = newpos[m];
  ((unsigned*)spnP8)[p*64 + lane] = pk;     // plain: k = 4*lane..+3
}

// ---------------- main fused GEMM (MX-fp8 K=128, 64 rows/wave, halved L2 staging) ----------------
// 256 threads = 4 waves; wave owns 64 rows x all 1024 cols (a[4][2] = 64 VGPR).
// BM=256, grid 512. Staging traffic HALVES vs R16 (512 blk x 4 waves x 256 KB
// = 512 MB) -- the vmcnt waits in R16/R19 pointed at L2 load, not unloaded
// latency. Per chunk: 8 MFMAs + 16-elem epilogue = 2x compute per wait.
// 256-thread blocks because the 512-thread allocator clamps at 64-76 VGPR
// (R8/R17/R19); at 256 threads it granted 172 spill-free (R6). A-prologue in
// 2 super-passes through the wave's 8 KB buffers before they recycle for B.

#define SBAR()   __builtin_amdgcn_s_barrier()
#define SFENCE() __builtin_amdgcn_sched_barrier(0)

__attribute__((amdgpu_waves_per_eu(1, 2)))
__launch_bounds__(256)
__global__ void k_main(const float* __restrict__ rp, const int* __restrict__ rawIdx,
                       const unsigned short* __restrict__ spnO, const unsigned char* __restrict__ spnP8,
                       const unsigned* __restrict__ packLab, const int* __restrict__ spLabel,
                       double* __restrict__ accum, int M){
  __shared__ __align__(16) char Bpriv[4*2*4096];   // 32 KB: per-wave 2x4 KB
  __shared__ float    posLt[256];
  __shared__ int      posLb[256];
  __shared__ unsigned cpLds[256];
  __shared__ float    lossW[4];

  const int tid  = threadIdx.x;
  const int lane = tid & 63, wid = tid >> 6;
  const int l15  = lane & 15, l4 = lane >> 4;
  const int rowBlock = blockIdx.x * 256;
  char* wb = Bpriv + wid*8192;                     // this wave's 2 buffers

  cpLds[tid] = packLab[tid];
  posLb[tid] = spLabel[rawIdx[rowBlock + tid]];    // one row per thread

  // ---- prologue: normalize 64 rows/wave -> fp8, 2 super-passes of 32 rows ----
  v8i a[4][2];   // [row-tile rt (16 rows)][K-half h]
  #pragma unroll
  for (int S = 0; S < 2; ++S){
    #pragma unroll
    for (int pp = 0; pp < 2; ++pp){
      const int rt = S*2 + pp;
      for (int it = 0; it < 4; ++it){
        const int rl = rt*16 + it*4 + l4;          // wave-local row
        const int t  = l15;
        const float* rpp = rp + (size_t)(rowBlock + wid*64 + rl)*DIM + t*16;
        const float4 v0 = *(const float4*)(rpp);
        const float4 v1 = *(const float4*)(rpp + 4);
        const float4 v2 = *(const float4*)(rpp + 8);
        const float4 v3 = *(const float4*)(rpp + 12);
        float ss = v0.x*v0.x + v0.y*v0.y + v0.z*v0.z + v0.w*v0.w
                 + v1.x*v1.x + v1.y*v1.y + v1.z*v1.z + v1.w*v1.w
                 + v2.x*v2.x + v2.y*v2.y + v2.z*v2.z + v2.w*v2.w
                 + v3.x*v3.x + v3.y*v3.y + v3.z*v3.z + v3.w*v3.w;
        const int sidx = rawIdx[rowBlock + wid*64 + rl];
        const uint4 s0 = *(const uint4*)(spnO + (size_t)sidx*DIM + t*16);
        const uint4 s1 = *(const uint4*)(spnO + (size_t)sidx*DIM + t*16 + 8);
        float dr =
          v0.x*bf2f(s0.x & 0xffff) + v0.y*bf2f(s0.x >> 16) +
          v0.z*bf2f(s0.y & 0xffff) + v0.w*bf2f(s0.y >> 16) +
          v1.x*bf2f(s0.z & 0xffff) + v1.y*bf2f(s0.z >> 16) +
          v1.z*bf2f(s0.w & 0xffff) + v1.w*bf2f(s0.w >> 16) +
          v2.x*bf2f(s1.x & 0xffff) + v2.y*bf2f(s1.x >> 16) +
          v2.z*bf2f(s1.y & 0xffff) + v2.w*bf2f(s1.y >> 16) +
          v3.x*bf2f(s1.z & 0xffff) + v3.y*bf2f(s1.z >> 16) +
          v3.z*bf2f(s1.w & 0xffff) + v3.w*bf2f(s1.w >> 16);
        ss += __shfl_xor(ss, 1); dr += __shfl_xor(dr, 1);
        ss += __shfl_xor(ss, 2); dr += __shfl_xor(dr, 2);
        ss += __shfl_xor(ss, 4); dr += __shfl_xor(dr, 4);
        ss += __shfl_xor(ss, 8); dr += __shfl_xor(dr, 8);
        const float rn = SCL / sqrtf(ss + 1e-12f);
        const int slot = pp*16 + it*4 + l4;        // slot within the 8 KB window
        const int swz  = (slot & 7) << 4;
        uint4 h;
        h.x = pk4fp8(v0.x*rn, v0.y*rn, v0.z*rn, v0.w*rn);
        h.y = pk4fp8(v1.x*rn, v1.y*rn, v1.z*rn, v1.w*rn);
        h.z = pk4fp8(v2.x*rn, v2.y*rn, v2.z*rn, v2.w*rn);
        h.w = pk4fp8(v3.x*rn, v3.y*rn, v3.z*rn, v3.w*rn);
        *(uint4*)(wb + slot*256 + ((t*16) ^ swz)) = h;
        if (l15 == 0) posLt[wid*64 + rl] = rn * dr;
      }
      // frag reads: slots written by THIS wave (same-wave LDS ordering)
      #pragma unroll
      for (int h = 0; h < 2; ++h){
        const int s   = pp*16 + l15;
        const int swz = (l15 & 7) << 4;
        const int off = (h*128 + l4*32) ^ swz;
        uint4 q0 = *(const uint4*)(wb + s*256 + off);
        uint4 q1 = *(const uint4*)(wb + s*256 + (off ^ 16));
        a[rt][h] = mkv8(q0, q1);
      }
    }
  }

  // row labels nibble-packed: ri = rt*4+e -> wave-local row rt*16 + l4*4 + e
  unsigned Lp0 = 0, Lp1 = 0;
  #pragma unroll
  for (int rt = 0; rt < 4; ++rt)
    #pragma unroll
    for (int e = 0; e < 4; ++e){
      unsigned lb = (unsigned)posLb[wid*64 + rt*16 + l4*4 + e];
      int ri = rt*4 + e;
      if (rt < 2) Lp0 |= lb << (ri*4);
      else        Lp1 |= lb << ((ri - 8)*4);
    }

  float sumT[16], sumO[16];
  #pragma unroll
  for (int i = 0; i < 16; ++i){ sumT[i] = 0.f; sumO[i] = 0.f; }

  // per-lane staging source bases: chunk c, col j -> bs[j] + c*4096
  const unsigned char* bs[4];
  #pragma unroll
  for (int j = 0; j < 4; ++j){
    const int colb = j*4 + l4;
    bs[j] = spnP8 + (size_t)colb*256 + ((l15 ^ (colb & 7)) << 4);
  }

  // all A-frag ds_reads landed before buffers get recycled (rule #18)
  asm volatile("s_waitcnt lgkmcnt(0)" ::: "memory");
  SFENCE();
  #pragma unroll
  for (int j = 0; j < 4; ++j) gload_lds16(bs[j],        wb        + j*1024);  // chunk 0
  #pragma unroll
  for (int j = 0; j < 4; ++j) gload_lds16(bs[j] + 4096, wb + 4096 + j*1024);  // chunk 1
  SBAR();                                  // cpLds/posLb visible (raw: keeps vmcnt)

  const int swzr = (l15 & 7) << 4;
  const int o0 = (l4*32) ^ swzr;
  const int o1 = (128 + l4*32) ^ swzr;

  // ---- K loop: 16 quads x 4 chunks, per-wave depth-2 pipeline, NO barriers ----
  for (int cq = 0; cq < 16; ++cq){
    const unsigned cpack = cpLds[cq*16 + l15];
    #pragma unroll
    for (int ci = 0; ci < 4; ++ci){
      const int c = cq*4 + ci;
      if (c < 63) asm volatile("s_waitcnt vmcnt(4)" ::: "memory");  // chunk c landed
      else        asm volatile("s_waitcnt vmcnt(0)" ::: "memory");
      SFENCE();
      char* buf = wb + (c & 1)*4096;
      const char* bp = buf + l15*256;
      v8i b0, b1;
      {
        uint4* pb0 = (uint4*)&b0;
        pb0[0] = *(const uint4*)(bp + o0);
        pb0[1] = *(const uint4*)(bp + (o0 ^ 16));
        uint4* pb1 = (uint4*)&b1;
        pb1[0] = *(const uint4*)(bp + o1);
        pb1[1] = *(const uint4*)(bp + (o1 ^ 16));
      }
      asm volatile("s_waitcnt lgkmcnt(0)" ::: "memory");   // b landed before overwrite
      SFENCE();
      if (c + 2 < 64){
        const size_t off = (size_t)(c + 2)*4096;
        #pragma unroll
        for (int j = 0; j < 4; ++j) gload_lds16(bs[j] + off, buf + j*1024);
      }

      f32x4 acc0 = (f32x4){0.f,0.f,0.f,0.f};
      f32x4 acc1 = (f32x4){0.f,0.f,0.f,0.f};
      f32x4 acc2 = (f32x4){0.f,0.f,0.f,0.f};
      f32x4 acc3 = (f32x4){0.f,0.f,0.f,0.f};
      __builtin_amdgcn_s_setprio(1);
      acc0 = MFMA128(a[0][0], b0, acc0);
      acc1 = MFMA128(a[1][0], b0, acc1);
      acc2 = MFMA128(a[2][0], b0, acc2);
      acc3 = MFMA128(a[3][0], b0, acc3);
      acc0 = MFMA128(a[0][1], b1, acc0);
      acc1 = MFMA128(a[1][1], b1, acc1);
      acc2 = MFMA128(a[2][1], b1, acc2);
      acc3 = MFMA128(a[3][1], b1, acc3);
      __builtin_amdgcn_s_setprio(0);

      const unsigned colLab = (cpack >> (ci*4)) & 15u;
      #pragma unroll
      for (int e = 0; e < 4; ++e){
        const float ev0 = __builtin_amdgcn_exp2f(acc0[e]);
        const float ev1 = __builtin_amdgcn_exp2f(acc1[e]);
        const float ev2 = __builtin_amdgcn_exp2f(acc2[e]);
        const float ev3 = __builtin_amdgcn_exp2f(acc3[e]);
        sumT[e]    += ev0;
        sumT[4+e]  += ev1;
        sumT[8+e]  += ev2;
        sumT[12+e] += ev3;
        sumO[e]    += (((Lp0 >> (e*4)) & 15u)     == colLab) ? ev0 : 0.f;
        sumO[4+e]  += (((Lp0 >> ((4+e)*4)) & 15u) == colLab) ? ev1 : 0.f;
        sumO[8+e]  += (((Lp1 >> (e*4)) & 15u)     == colLab) ? ev2 : 0.f;
        sumO[12+e] += (((Lp1 >> ((4+e)*4)) & 15u) == colLab) ? ev3 : 0.f;
      }
    }
  }

  // reduce over the 16 l15-lanes sharing each row
  #pragma unroll
  for (int i = 0; i < 16; ++i){
    #pragma unroll
    for (int o = 1; o < 16; o <<= 1){
      sumT[i] += __shfl_xor(sumT[i], o);
      sumO[i] += __shfl_xor(sumO[i], o);
    }
  }

  // finish in log2 domain: loss_i = ln2 * (log2(den) - pl2); ln2 folded into k_final
  float part = 0.f;
  #pragma unroll
  for (int rt = 0; rt < 4; ++rt)
    #pragma unroll
    for (int e = 0; e < 4; ++e){
      const float pl  = posLt[wid*64 + rt*16 + l4*4 + e];
      const float ep  = __builtin_amdgcn_exp2f(pl);
      const float den = ep + (sumT[rt*4+e] - sumO[rt*4+e]) + 1e-8f;
      part += __builtin_amdgcn_logf(den) - pl;   // v_log_f32 = log2
    }
  part = (l15 == 0) ? part : 0.f;
  #pragma unroll
  for (int o = 1; o < 64; o <<= 1) part += __shfl_xor(part, o);
  if (lane == 0) lossW[wid] = part;
  __syncthreads();
  if (tid == 0){
    float s = 0.f;
    #pragma unroll
    for (int i = 0; i < 4; ++i) s += lossW[i];
    atomicAdd(accum, (double)s);   // ONE atomic per block
  }
}

__global__ void k_final(const double* __restrict__ accum, float* __restrict__ out, int N){
  out[0] = (float)((*accum / (double)N) * (0.07 * 0.6931471805599453));
}

// ---------------- launch ----------------

extern "C" void kernel_launch(void* const* d_in, const int* in_sizes, int n_in,
                              void* d_out, int out_size, void* d_ws, size_t ws_size,
                              hipStream_t stream){
  const float* sp  = (const float*)d_in[0];
  const float* rp  = (const float*)d_in[1];
  const int*   idx = (const int*)d_in[2];
  const int*   lab = (const int*)d_in[3];
  const int M = in_sizes[0] / DIM;     // 1024
  const int N = in_sizes[2];           // 131072

  char* ws = (char*)d_ws;
  size_t off = 0;
  auto alloc = [&](size_t bytes){ void* p = ws + off; off = (off + bytes + 255) & ~(size_t)255; return p; };
  int*      counts  = (int*)     alloc((size_t)M * NCLS * 4);
  int*      spLabel = (int*)     alloc((size_t)M * 4);
  int*      newpos  = (int*)     alloc((size_t)M * 4);
  unsigned* packLab = (unsigned*)alloc((size_t)(M/64) * 16 * 4);
  double*   accum   = (double*)  alloc(16);
  unsigned short* spnO = (unsigned short*)alloc((size_t)M * DIM * 2);
  unsigned char*  spnP8 = (unsigned char*)alloc((size_t)M * DIM);

  k_zero<<<(M*NCLS + 255)/256, 256, 0, stream>>>(counts, packLab, accum, M*NCLS, (M/64)*16);
  k_hist<<<(N + 255)/256, 256, 0, stream>>>(idx, lab, counts, N);
  k_label_perm<<<1, M, 0, stream>>>(counts, spLabel, newpos, packLab);
  k_norm_sp<<<M, 64, 0, stream>>>(sp, newpos, spnO, spnP8);
  k_main<<<N/256, 256, 0, stream>>>(rp, idx, spnO, spnP8, packLab, spLabel, accum, M);
  k_final<<<1, 1, 0, stream>>>(accum, (float*)d_out, N);
}